// Round 14
// baseline (256.635 us; speedup 1.0000x reference)
//
#include <hip/hip_runtime.h>
#include <math.h>

#define NB 8
#define NA 720
#define NQ 180           // angle quads {q, 719-q, 359-q, 360+q}
#define ND 1024
#define NH 512
#define NW 512

// DS = 4/1024 -> 1/DS = 256. S0 = -2 + DS/2 -> -S0/DS = 511.5
#define DXF 0.00390625f
#define IMG_MIN_F (-1.0f)
#define DTH_D (3.14159265358979323846 / 720.0)

#define TI 32            // table tile: 32 top rows
#define TJ 32            // table tile: 32 cols
#define WIN 64           // staged window elements; u_local stays in [1, ~52]

typedef unsigned int uint32;
typedef __fp16 half2v __attribute__((ext_vector_type(2)));   // matches cvt_pkrtz return

// ---------------- Kernel 1: quad conv -> G4, with table fused into blocks 0..89 ----------
// G4[b][q][d] (uint4): word r = pack(y_r[d], y_r[d+1]) f16x2, rows {q,719-q,359-q,360+q}.
// tpr[t][q] = (256cos, 256sin, 511.5-b1, 511.5-b2)
__global__ __launch_bounds__(256) void conv_table_kernel(const float* __restrict__ x,
                                                         const float* __restrict__ w,
                                                         uint4* __restrict__ G4,
                                                         float4* __restrict__ tpr) {
    int id = blockIdx.x;                  // b*180 + q over 1440 blocks
    int b = id / NQ;
    int q = id - b * NQ;
    int rows[4] = {q, 719 - q, 359 - q, 360 + q};

    __shared__ float s[4][16 + ND + 16];
    __shared__ float wk[16];

    int tid = threadIdx.x;                // 256 threads
    if (tid < 16) {
#pragma unroll
        for (int r = 0; r < 4; ++r) { s[r][tid] = 0.0f; s[r][16 + ND + tid] = 0.0f; }
    }
    if (tid < 11) wk[tid] = w[tid] * (float)DTH_D;

#pragma unroll
    for (int r = 0; r < 4; ++r) {
        const float* xr = x + ((size_t)b * NA + rows[r]) * ND;
        *(float4*)&s[r][16 + tid * 4] = ((const float4*)xr)[tid];
    }
    __syncthreads();

    int d0 = tid * 4;
    uint32 wrd[4][4];
#pragma unroll
    for (int r = 0; r < 4; ++r) {
        float o[5];
#pragma unroll
        for (int t = 0; t < 5; ++t) {
            float acc = 0.f;
#pragma unroll
            for (int k = 0; k < 11; ++k) acc = fmaf(wk[k], s[r][6 + d0 + t + k], acc);
            o[t] = acc;
        }
        union { _Float16 hf; unsigned short us; } cv;
        unsigned short h[5];
#pragma unroll
        for (int t = 0; t < 5; ++t) { cv.hf = (_Float16)o[t]; h[t] = cv.us; }
#pragma unroll
        for (int t = 0; t < 4; ++t) wrd[r][t] = (uint32)h[t] | ((uint32)h[t + 1] << 16);
    }
    uint4* gout = G4 + ((size_t)b * NQ + q) * ND + d0;
#pragma unroll
    for (int t = 0; t < 4; ++t)
        gout[t] = make_uint4(wrd[0][t], wrd[1][t], wrd[2][t], wrd[3][t]);

    // ---- fused table work: blocks 0..89 compute one tpr entry per thread ----
    if (id < 90) {
        int idx = id * 256 + tid;             // 180 quads * 128 tiles = 23040
        int tq = idx >> 7;
        int tt = idx & 127;
        float th = (float)((tq + 0.5) * DTH_D);   // THETAS f64->f32 like reference
        double thd = (double)th;
        float ca = (float)(cos(thd) * 256.0);
        float sa = (float)(sin(thd) * 256.0);

        int it = tt >> 4, jt = tt & 15;
        int ibase = it * TI, jbase = jt * TJ;
        float pi_lo = IMG_MIN_F + (ibase + 0.5f) * DXF;
        float pi_hi = IMG_MIN_F + (ibase + TI - 0.5f) * DXF;
        float pj_lo = IMG_MIN_F + (jbase + 0.5f) * DXF;
        float pj_hi = IMG_MIN_F + (jbase + TJ - 0.5f) * DXF;
        float sj = fminf(pj_lo * sa, pj_hi * sa);
        float umin1 = 511.5f + fminf(pi_lo * ca, pi_hi * ca) + sj;
        float umin2 = 511.5f + fminf(-pi_lo * ca, -pi_hi * ca) + sj;
        int b1 = ((int)floorf(umin1) - 1) & ~3;   // 4-elem align -> 64B align in G4
        int b2 = ((int)floorf(umin2) - 1) & ~3;
        b1 = max(0, min(b1, ND - WIN));
        b2 = max(0, min(b2, ND - WIN));
        tpr[(size_t)tt * NQ + tq] =
            make_float4(ca, sa, 511.5f - (float)b1, 511.5f - (float)b2);
    }
}

// ---------------- Kernel 2: backprojection, 4-fold symmetry, atomic scatter --------------
// Inner loop identical to R12 (155 us verified). Epilogue: 12 unsafeAtomicAdd into the
// harness-zeroed `out` (each pixel gets exactly 3 adds: T/M + 2 transpose partials) --
// replaces PB/PC partial images + combine kernel.

__device__ __forceinline__ void async_ld16(const float* g, float* l) {
    __builtin_amdgcn_global_load_lds((const __attribute__((address_space(1))) void*)g,
                                     (__attribute__((address_space(3))) void*)l,
                                     16, 0, 0);
}

#define WAIT_VM0_BARRIER() do { \
    asm volatile("" ::: "memory"); \
    __builtin_amdgcn_s_waitcnt(0x0F70); /* vmcnt(0) only */ \
    __builtin_amdgcn_s_barrier(); \
    asm volatile("" ::: "memory"); \
} while (0)

// acc(f32) += taps.lo16 * gf.lo + taps.hi16 * gf.hi   (one VOP3P dot2)
#define DOT2(acc_, taps_, gf_) \
    asm("v_dot2_f32_f16 %0, %1, %2, %0" : "+v"(acc_) : "v"(taps_), "v"(gf_))

__global__ __launch_bounds__(256, 8) void bp_kernel(const uint4* __restrict__ G4,
                                                    const float4* __restrict__ tpr,
                                                    float* __restrict__ out) {
    int bid = blockIdx.x;
    // XCD-chunked swizzle (2048 = 8*256, bijective): XCD x -> all 256 blocks of batch x
    int lb = (bid & 7) * 256 + (bid >> 3);
    int b = lb >> 8;             // batch 0..7
    int t16 = lb & 255;          // 16-row x 32-col half-tile id
    int it16 = t16 >> 4;         // 0..15 over top-half rows
    int jt = t16 & 15;
    int ibase = it16 * 16, jbase = jt * 32;
    int tile32 = (it16 >> 1) * 16 + jt;      // table tile (32x32)

    int tid = threadIdx.x;
    int lane = tid & 63;
    int wv = tid >> 6;           // 0..3 -> stages quad c*4+wv
    int jj = lane & 31;
    int hi = lane >> 5;          // 0/1 -> +1 row

    int j = jbase + jj;
    float pxj = IMG_MIN_F + (j + 0.5f) * DXF;
    int i0 = ibase + 2 * wv + hi;           // +8*r, r=0..1
    float pxi = IMG_MIN_F + (i0 + 0.5f) * DXF;

    __shared__ __align__(16) uint4 buf[2][4][2][WIN];   // 2*4*2*64*16 = 16384 B

    const uint4* gp = G4 + (size_t)b * (NQ * ND);
    const float4* tp = tpr + (size_t)tile32 * NQ;

    float accT[2] = {0.f, 0.f};             // (i,j)          angles q, 719-q
    float accM[2] = {0.f, 0.f};             // (511-i,j)      angles q, 719-q
    float accB1[2] = {0.f, 0.f};            // (j,i)          angles 359-q (u1)
    float accB2[2] = {0.f, 0.f};            // (511-j,i)      angles 360+q (u1)
    float accB3[2] = {0.f, 0.f};            // (j,511-i)      angles 359-q (u2)
    float accB4[2] = {0.f, 0.f};            // (511-j,511-i)  angles 360+q (u2)

#define STAGE(c_, bs_) do { \
    int q_ = (c_) * 4 + wv; \
    float4 t4_ = tp[q_]; \
    int b1_ = (int)(511.5f - t4_.z); \
    int b2_ = (int)(511.5f - t4_.w); \
    const float* g1_ = (const float*)(gp + (size_t)q_ * ND + b1_) + lane * 4; \
    const float* g2_ = (const float*)(gp + (size_t)q_ * ND + b2_) + lane * 4; \
    async_ld16(g1_, (float*)&buf[bs_][wv][0][0]); \
    async_ld16(g2_, (float*)&buf[bs_][wv][1][0]); \
} while (0)

    STAGE(0, 0);
    WAIT_VM0_BARRIER();

    for (int c = 0; c < 45; ++c) {
        int cur = c & 1;
        if (c + 1 < 45) STAGE(c + 1, cur ^ 1);   // 2 async DMAs per wave
#pragma unroll
        for (int k = 0; k < 4; ++k) {
            float4 t4 = tp[c * 4 + k];         // uniform -> s_load_dwordx4
            float du = t4.x * (8.0f * DXF);
            float u1 = fmaf(pxj, t4.y, fmaf(pxi, t4.x, t4.z));    // local in W1
            float u2 = fmaf(pxj, t4.y, fmaf(pxi, -t4.x, t4.w));   // local in W2
            const uint4* W1 = &buf[cur][k][0][0];
            const uint4* W2 = &buf[cur][k][1][0];
#pragma unroll
            for (int r = 0; r < 2; ++r) {
                // ---- u1: rows {q -> T, 719-q -> M, 359-q -> B1, 360+q -> B2}
                int iu1 = (int)u1;                    // u1 in [1,52): trunc == floor
                float f1 = __builtin_amdgcn_fractf(u1);
                half2v pk1 = __builtin_amdgcn_cvt_pkrtz(1.0f - f1, f1);
                uint4 v1 = W1[iu1];                   // one ds_read_b128
                DOT2(accT[r],  v1.x, pk1);
                DOT2(accM[r],  v1.y, pk1);
                DOT2(accB1[r], v1.z, pk1);
                DOT2(accB2[r], v1.w, pk1);

                // ---- u2: rows {q -> M, 719-q -> T, 359-q -> B3, 360+q -> B4}
                int iu2 = (int)u2;
                float f2 = __builtin_amdgcn_fractf(u2);
                half2v pk2 = __builtin_amdgcn_cvt_pkrtz(1.0f - f2, f2);
                uint4 v2 = W2[iu2];                   // one ds_read_b128
                DOT2(accM[r],  v2.x, pk2);
                DOT2(accT[r],  v2.y, pk2);
                DOT2(accB3[r], v2.z, pk2);
                DOT2(accB4[r], v2.w, pk2);

                u1 += du;
                u2 -= du;
            }
        }
        WAIT_VM0_BARRIER();                    // drain this chunk's DMAs, swap buffers
    }

    // Atomic scatter into harness-zeroed out: each pixel receives exactly 3 adds.
    float* orow = out + (size_t)b * (NH * NW);
#pragma unroll
    for (int r = 0; r < 2; ++r) {
        int i = i0 + 8 * r;
        unsafeAtomicAdd(&orow[i * NW + j], accT[r]);
        unsafeAtomicAdd(&orow[(511 - i) * NW + j], accM[r]);
        unsafeAtomicAdd(&orow[j * NW + i], accB1[r]);
        unsafeAtomicAdd(&orow[j * NW + (511 - i)], accB3[r]);
        unsafeAtomicAdd(&orow[(511 - j) * NW + i], accB2[r]);
        unsafeAtomicAdd(&orow[(511 - j) * NW + (511 - i)], accB4[r]);
    }
#undef STAGE
}

extern "C" void kernel_launch(void* const* d_in, const int* in_sizes, int n_in,
                              void* d_out, int out_size, void* d_ws, size_t ws_size,
                              hipStream_t stream) {
    const float* x = (const float*)d_in[0];      // [8,1,720,1024] f32
    const float* w = (const float*)d_in[1];      // [1,1,1,11] f32
    float* out = (float*)d_out;                  // [8,1,512,512] f32

    char* ws = (char*)d_ws;
    uint4* G4 = (uint4*)ws;                                  // 8*180*1024*16 = 23.6 MB
    float4* tpr = (float4*)(ws + (size_t)NB * NQ * ND * 16); // 128*180*16 = 368 KB

    conv_table_kernel<<<dim3(NB * NQ), dim3(256), 0, stream>>>(x, w, G4, tpr);
    bp_kernel<<<dim3(2048), dim3(256), 0, stream>>>(G4, tpr, out);
}

// Round 15
// 216.741 us; speedup vs baseline: 1.1841x; 1.1841x over previous
//
#include <hip/hip_runtime.h>
#include <math.h>

#define NB 8
#define NA 720
#define NQ 180           // angle quads {q, 719-q, 359-q, 360+q}
#define ND 1024
#define NH 512
#define NW 512

// DS = 4/1024 -> 1/DS = 256. S0 = -2 + DS/2 -> -S0/DS = 511.5
#define DXF 0.00390625f
#define IMG_MIN_F (-1.0f)
#define DTH_D (3.14159265358979323846 / 720.0)

#define TI 32            // table tile: 32 top rows
#define TJ 32            // table tile: 32 cols
#define WIN 64           // staged window elements; u_local stays in [1, ~52]

typedef unsigned int uint32;
typedef __fp16 half2v __attribute__((ext_vector_type(2)));   // matches cvt_pkrtz return

// ---------------- Kernel 1: quad conv -> G4, with table fused into blocks 0..89 ----------
// G4[b][q][d] (uint4): word r = pack(y_r[d], y_r[d+1]) f16x2, rows {q,719-q,359-q,360+q}.
// tpr[t][q] = (256cos, 256sin, 511.5-b1, 511.5-b2)
__global__ __launch_bounds__(256) void conv_table_kernel(const float* __restrict__ x,
                                                         const float* __restrict__ w,
                                                         uint4* __restrict__ G4,
                                                         float4* __restrict__ tpr) {
    int id = blockIdx.x;                  // b*180 + q over 1440 blocks
    int b = id / NQ;
    int q = id - b * NQ;
    int rows[4] = {q, 719 - q, 359 - q, 360 + q};

    __shared__ float s[4][16 + ND + 16];
    __shared__ float wk[16];

    int tid = threadIdx.x;                // 256 threads
    if (tid < 16) {
#pragma unroll
        for (int r = 0; r < 4; ++r) { s[r][tid] = 0.0f; s[r][16 + ND + tid] = 0.0f; }
    }
    if (tid < 11) wk[tid] = w[tid] * (float)DTH_D;

#pragma unroll
    for (int r = 0; r < 4; ++r) {
        const float* xr = x + ((size_t)b * NA + rows[r]) * ND;
        *(float4*)&s[r][16 + tid * 4] = ((const float4*)xr)[tid];
    }
    __syncthreads();

    int d0 = tid * 4;
    uint32 wrd[4][4];
#pragma unroll
    for (int r = 0; r < 4; ++r) {
        float o[5];
#pragma unroll
        for (int t = 0; t < 5; ++t) {
            float acc = 0.f;
#pragma unroll
            for (int k = 0; k < 11; ++k) acc = fmaf(wk[k], s[r][6 + d0 + t + k], acc);
            o[t] = acc;
        }
        union { _Float16 hf; unsigned short us; } cv;
        unsigned short h[5];
#pragma unroll
        for (int t = 0; t < 5; ++t) { cv.hf = (_Float16)o[t]; h[t] = cv.us; }
#pragma unroll
        for (int t = 0; t < 4; ++t) wrd[r][t] = (uint32)h[t] | ((uint32)h[t + 1] << 16);
    }
    uint4* gout = G4 + ((size_t)b * NQ + q) * ND + d0;
#pragma unroll
    for (int t = 0; t < 4; ++t)
        gout[t] = make_uint4(wrd[0][t], wrd[1][t], wrd[2][t], wrd[3][t]);

    // ---- fused table work: blocks 0..89 compute one tpr entry per thread ----
    if (id < 90) {
        int idx = id * 256 + tid;             // 180 quads * 128 tiles = 23040
        int tq = idx >> 7;
        int tt = idx & 127;
        float th = (float)((tq + 0.5) * DTH_D);   // THETAS f64->f32 like reference
        double thd = (double)th;
        float ca = (float)(cos(thd) * 256.0);
        float sa = (float)(sin(thd) * 256.0);

        int it = tt >> 4, jt = tt & 15;
        int ibase = it * TI, jbase = jt * TJ;
        float pi_lo = IMG_MIN_F + (ibase + 0.5f) * DXF;
        float pi_hi = IMG_MIN_F + (ibase + TI - 0.5f) * DXF;
        float pj_lo = IMG_MIN_F + (jbase + 0.5f) * DXF;
        float pj_hi = IMG_MIN_F + (jbase + TJ - 0.5f) * DXF;
        float sj = fminf(pj_lo * sa, pj_hi * sa);
        float umin1 = 511.5f + fminf(pi_lo * ca, pi_hi * ca) + sj;
        float umin2 = 511.5f + fminf(-pi_lo * ca, -pi_hi * ca) + sj;
        int b1 = ((int)floorf(umin1) - 1) & ~3;   // 4-elem align -> 64B align in G4
        int b2 = ((int)floorf(umin2) - 1) & ~3;
        b1 = max(0, min(b1, ND - WIN));
        b2 = max(0, min(b2, ND - WIN));
        tpr[(size_t)tt * NQ + tq] =
            make_float4(ca, sa, 511.5f - (float)b1, 511.5f - (float)b2);
    }
}

// ---------------- Kernel 2: backprojection, 4-fold symmetry (R12-verified epilogue) ------
// One u-group = 1 ds_read_b128 (4 rows x 2 taps) + 1 pkrtz + 4 v_dot2 = 4 samples.
// T/M plain-stored to out; transpose-slot partials plain-stored to PB/PC (write-once,
// L2-coalesced); combine kernel adds them. NO atomics (R14 showed 3x RMW write-amp).

__device__ __forceinline__ void async_ld16(const float* g, float* l) {
    __builtin_amdgcn_global_load_lds((const __attribute__((address_space(1))) void*)g,
                                     (__attribute__((address_space(3))) void*)l,
                                     16, 0, 0);
}

#define WAIT_VM0_BARRIER() do { \
    asm volatile("" ::: "memory"); \
    __builtin_amdgcn_s_waitcnt(0x0F70); /* vmcnt(0) only */ \
    __builtin_amdgcn_s_barrier(); \
    asm volatile("" ::: "memory"); \
} while (0)

// acc(f32) += taps.lo16 * gf.lo + taps.hi16 * gf.hi   (one VOP3P dot2)
#define DOT2(acc_, taps_, gf_) \
    asm("v_dot2_f32_f16 %0, %1, %2, %0" : "+v"(acc_) : "v"(taps_), "v"(gf_))

__global__ __launch_bounds__(256, 8) void bp_kernel(const uint4* __restrict__ G4,
                                                    const float4* __restrict__ tpr,
                                                    float* __restrict__ out,
                                                    float* __restrict__ PB,
                                                    float* __restrict__ PC) {
    int bid = blockIdx.x;
    // XCD-chunked swizzle (2048 = 8*256, bijective): XCD x -> all 256 blocks of batch x
    int lb = (bid & 7) * 256 + (bid >> 3);
    int b = lb >> 8;             // batch 0..7
    int t16 = lb & 255;          // 16-row x 32-col half-tile id
    int it16 = t16 >> 4;         // 0..15 over top-half rows
    int jt = t16 & 15;
    int ibase = it16 * 16, jbase = jt * 32;
    int tile32 = (it16 >> 1) * 16 + jt;      // table tile (32x32)

    int tid = threadIdx.x;
    int lane = tid & 63;
    int wv = tid >> 6;           // 0..3 -> stages quad c*4+wv
    int jj = lane & 31;
    int hi = lane >> 5;          // 0/1 -> +1 row

    int j = jbase + jj;
    float pxj = IMG_MIN_F + (j + 0.5f) * DXF;
    int i0 = ibase + 2 * wv + hi;           // +8*r, r=0..1
    float pxi = IMG_MIN_F + (i0 + 0.5f) * DXF;

    __shared__ __align__(16) uint4 buf[2][4][2][WIN];   // 2*4*2*64*16 = 16384 B

    const uint4* gp = G4 + (size_t)b * (NQ * ND);
    const float4* tp = tpr + (size_t)tile32 * NQ;

    float accT[2] = {0.f, 0.f};             // (i,j)          angles q, 719-q
    float accM[2] = {0.f, 0.f};             // (511-i,j)      angles q, 719-q
    float accB1[2] = {0.f, 0.f};            // (j,i)          angles 359-q (u1)
    float accB2[2] = {0.f, 0.f};            // (511-j,i)      angles 360+q (u1)
    float accB3[2] = {0.f, 0.f};            // (j,511-i)      angles 359-q (u2)
    float accB4[2] = {0.f, 0.f};            // (511-j,511-i)  angles 360+q (u2)

#define STAGE(c_, bs_) do { \
    int q_ = (c_) * 4 + wv; \
    float4 t4_ = tp[q_]; \
    int b1_ = (int)(511.5f - t4_.z); \
    int b2_ = (int)(511.5f - t4_.w); \
    const float* g1_ = (const float*)(gp + (size_t)q_ * ND + b1_) + lane * 4; \
    const float* g2_ = (const float*)(gp + (size_t)q_ * ND + b2_) + lane * 4; \
    async_ld16(g1_, (float*)&buf[bs_][wv][0][0]); \
    async_ld16(g2_, (float*)&buf[bs_][wv][1][0]); \
} while (0)

    STAGE(0, 0);
    WAIT_VM0_BARRIER();

    for (int c = 0; c < 45; ++c) {
        int cur = c & 1;
        if (c + 1 < 45) STAGE(c + 1, cur ^ 1);   // 2 async DMAs per wave
#pragma unroll
        for (int k = 0; k < 4; ++k) {
            float4 t4 = tp[c * 4 + k];         // uniform -> s_load_dwordx4
            float du = t4.x * (8.0f * DXF);
            float u1 = fmaf(pxj, t4.y, fmaf(pxi, t4.x, t4.z));    // local in W1
            float u2 = fmaf(pxj, t4.y, fmaf(pxi, -t4.x, t4.w));   // local in W2
            const uint4* W1 = &buf[cur][k][0][0];
            const uint4* W2 = &buf[cur][k][1][0];
#pragma unroll
            for (int r = 0; r < 2; ++r) {
                // ---- u1: rows {q -> T, 719-q -> M, 359-q -> B1, 360+q -> B2}
                int iu1 = (int)u1;                    // u1 in [1,52): trunc == floor
                float f1 = __builtin_amdgcn_fractf(u1);
                half2v pk1 = __builtin_amdgcn_cvt_pkrtz(1.0f - f1, f1);
                uint4 v1 = W1[iu1];                   // one ds_read_b128
                DOT2(accT[r],  v1.x, pk1);
                DOT2(accM[r],  v1.y, pk1);
                DOT2(accB1[r], v1.z, pk1);
                DOT2(accB2[r], v1.w, pk1);

                // ---- u2: rows {q -> M, 719-q -> T, 359-q -> B3, 360+q -> B4}
                int iu2 = (int)u2;
                float f2 = __builtin_amdgcn_fractf(u2);
                half2v pk2 = __builtin_amdgcn_cvt_pkrtz(1.0f - f2, f2);
                uint4 v2 = W2[iu2];                   // one ds_read_b128
                DOT2(accM[r],  v2.x, pk2);
                DOT2(accT[r],  v2.y, pk2);
                DOT2(accB3[r], v2.z, pk2);
                DOT2(accB4[r], v2.w, pk2);

                u1 += du;
                u2 -= du;
            }
        }
        WAIT_VM0_BARRIER();                    // drain this chunk's DMAs, swap buffers
    }

    float* orow = out + (size_t)b * (NH * NW);
    float* pbb = PB + (size_t)b * (NH * NW);
    float* pcc = PC + (size_t)b * (NH * NW);
#pragma unroll
    for (int r = 0; r < 2; ++r) {
        int i = i0 + 8 * r;
        orow[i * NW + j] = accT[r];
        orow[(511 - i) * NW + j] = accM[r];
        pbb[j * NW + i] = accB1[r];
        pbb[j * NW + (511 - i)] = accB3[r];
        pcc[(511 - j) * NW + i] = accB2[r];
        pcc[(511 - j) * NW + (511 - i)] = accB4[r];
    }
#undef STAGE
}

// ---------------- Kernel 3: out += PB + PC ----------------------------------------------
__global__ __launch_bounds__(256) void combine_kernel(float4* __restrict__ out,
                                                      const float4* __restrict__ PB,
                                                      const float4* __restrict__ PC) {
    size_t idx = (size_t)blockIdx.x * 256 + threadIdx.x;  // 2048*256 = 8*512*512/4
    float4 o = out[idx];
    float4 pb = PB[idx];
    float4 pc = PC[idx];
    o.x += pb.x + pc.x;
    o.y += pb.y + pc.y;
    o.z += pb.z + pc.z;
    o.w += pb.w + pc.w;
    out[idx] = o;
}

extern "C" void kernel_launch(void* const* d_in, const int* in_sizes, int n_in,
                              void* d_out, int out_size, void* d_ws, size_t ws_size,
                              hipStream_t stream) {
    const float* x = (const float*)d_in[0];      // [8,1,720,1024] f32
    const float* w = (const float*)d_in[1];      // [1,1,1,11] f32
    float* out = (float*)d_out;                  // [8,1,512,512] f32

    char* ws = (char*)d_ws;
    uint4* G4 = (uint4*)ws;                                  // 8*180*1024*16 = 23.6 MB
    float4* tpr = (float4*)(ws + (size_t)NB * NQ * ND * 16); // 128*180*16 = 368 KB
    float* PB = (float*)((char*)tpr + (size_t)128 * NQ * 16);
    float* PC = PB + (size_t)NB * NH * NW;                   // 8.39 MB each

    conv_table_kernel<<<dim3(NB * NQ), dim3(256), 0, stream>>>(x, w, G4, tpr);
    bp_kernel<<<dim3(2048), dim3(256), 0, stream>>>(G4, tpr, out, PB, PC);
    combine_kernel<<<dim3(2048), dim3(256), 0, stream>>>((float4*)out,
                                                         (const float4*)PB,
                                                         (const float4*)PC);
}